// Round 7
// baseline (213.666 us; speedup 1.0000x reference)
//
#include <hip/hip_runtime.h>
#include <hip/hip_bf16.h>
#include <cmath>

#define ALPHA 1.702f
#define LIMIT 7.0f

constexpr int B = 2, S = 1024, H = 768, E = 8, I = 768;
constexpr int T = B * S;          // 2048 tokens
constexpr int TWO_I = 2 * I;      // 1536
constexpr int CAP = T;            // per-expert row capacity
constexpr int NROWS = T * 2;      // 4096 (token, expert) entries

typedef __attribute__((ext_vector_type(8))) short short8;
typedef __attribute__((ext_vector_type(4))) float floatx4;

__device__ __forceinline__ unsigned short f2bf(float v) {
  __hip_bfloat16 h = __float2bfloat16(v);
  return *reinterpret_cast<unsigned short*>(&h);
}

// async global->LDS, 16B per lane. LDS dst is wave-uniform base + lane*16.
__device__ __forceinline__ void g2l16(const void* g, void* l) {
  __builtin_amdgcn_global_load_lds(
      (const __attribute__((address_space(1))) void*)g,
      (__attribute__((address_space(3))) void*)l, 16, 0, 0);
}

// ---------------------------------------------------------------------------
// Router: 1 wave/token. Fused: logits+top2+softmax, bf16 cast of x,
// zero-init of out row. No global atomics.
// ---------------------------------------------------------------------------
__global__ __launch_bounds__(64) void router_kernel(
    const float* __restrict__ x, const float* __restrict__ Wr,
    const float* __restrict__ br, int* __restrict__ topk_idx,
    float* __restrict__ topk_w, unsigned short* __restrict__ xb,
    float* __restrict__ out) {
  int t = blockIdx.x;
  int lane = threadIdx.x;  // 0..63
  const float* xr = x + (size_t)t * H;

  float4 z4 = {0.f, 0.f, 0.f, 0.f};
#pragma unroll
  for (int j = 0; j < 3; j++)
    *(float4*)(out + (size_t)t * H + (size_t)(j * 64 + lane) * 4) = z4;

  float acc[E];
#pragma unroll
  for (int e = 0; e < E; e++) acc[e] = 0.0f;

#pragma unroll
  for (int it = 0; it < 3; it++) {
    int h4 = it * 64 + lane;  // float4 index into the row
    float4 xv = *(const float4*)(xr + (size_t)h4 * 4);
    ushort4 xo;
    xo.x = f2bf(xv.x);
    xo.y = f2bf(xv.y);
    xo.z = f2bf(xv.z);
    xo.w = f2bf(xv.w);
    *(ushort4*)(xb + (size_t)t * H + (size_t)h4 * 4) = xo;
    const float* wrow = Wr + (size_t)h4 * 4 * E;
    float xs[4] = {xv.x, xv.y, xv.z, xv.w};
#pragma unroll
    for (int j = 0; j < 4; j++)
#pragma unroll
      for (int e = 0; e < E; e++) acc[e] += xs[j] * wrow[j * E + e];
  }
#pragma unroll
  for (int e = 0; e < E; e++) {
    float v = acc[e];
    for (int off = 32; off > 0; off >>= 1) v += __shfl_down(v, off, 64);
    acc[e] = v;
  }
  if (lane == 0) {
    float logits[E];
#pragma unroll
    for (int e = 0; e < E; e++) logits[e] = acc[e] + br[e];
    int i0 = 0;
    float v0 = logits[0];
#pragma unroll
    for (int e = 1; e < E; e++)
      if (logits[e] > v0) { v0 = logits[e]; i0 = e; }
    int i1 = -1;
    float v1 = -INFINITY;
#pragma unroll
    for (int e = 0; e < E; e++) {
      if (e == i0) continue;
      if (logits[e] > v1) { v1 = logits[e]; i1 = e; }
    }
    float s1 = __expf(v1 - v0);
    float denom = 1.0f + s1;
    topk_idx[t * 2 + 0] = i0;
    topk_idx[t * 2 + 1] = i1;
    topk_w[t * 2 + 0] = 1.0f / denom;
    topk_w[t * 2 + 1] = s1 / denom;
  }
}

// ---------------------------------------------------------------------------
// Transpose + cast both weight tensors; z==16 slice = single-block
// assignment pass (LDS atomics), hidden under this dispatch.
// ---------------------------------------------------------------------------
__global__ __launch_bounds__(256) void transpose_all(
    const float* __restrict__ Wgu, const float* __restrict__ Wd,
    unsigned short* __restrict__ Wgt, unsigned short* __restrict__ Wdt,
    const int* __restrict__ topk_idx, const float* __restrict__ topk_w,
    int* __restrict__ e_cnt, int* __restrict__ row_token,
    float* __restrict__ row_w) {
  int z = blockIdx.z;
  int tid = threadIdx.x;

  if (z == 16) {
    if (blockIdx.x != 0 || blockIdx.y != 0) return;
    __shared__ int cur[E];
    if (tid < E) cur[tid] = 0;
    __syncthreads();
    for (int i = tid; i < NROWS; i += 256) {
      int e = topk_idx[i];
      int pos = atomicAdd(&cur[e], 1);
      row_token[e * CAP + pos] = i >> 1;
      row_w[e * CAP + pos] = topk_w[i];
    }
    __syncthreads();
    if (tid < E) e_cnt[tid] = cur[tid];
    return;
  }

  int which = z >> 3, e = z & 7;
  int N = which ? H : TWO_I;
  if (which && blockIdx.x >= (H / 64)) return;
  const float* in = which ? (Wd + (size_t)e * H * I)
                          : (Wgu + (size_t)e * H * TWO_I);
  unsigned short* out = which ? (Wdt + (size_t)e * H * I)
                              : (Wgt + (size_t)e * H * TWO_I);
  constexpr int K = 768;
  int n0 = blockIdx.x * 64, k0 = blockIdx.y * 64;

  __shared__ float tile[64][65];
  int jr = tid & 15, r0 = tid >> 4;
#pragma unroll
  for (int p = 0; p < 4; p++) {
    int k = r0 + p * 16;
    float4 v = *(const float4*)(in + (size_t)(k0 + k) * N + n0 + jr * 4);
    tile[k][jr * 4 + 0] = v.x;
    tile[k][jr * 4 + 1] = v.y;
    tile[k][jr * 4 + 2] = v.z;
    tile[k][jr * 4 + 3] = v.w;
  }
  __syncthreads();
#pragma unroll
  for (int p = 0; p < 4; p++) {
    int n = r0 + p * 16;
    ushort4 o;
    o.x = f2bf(tile[jr * 4 + 0][n]);
    o.y = f2bf(tile[jr * 4 + 1][n]);
    o.z = f2bf(tile[jr * 4 + 2][n]);
    o.w = f2bf(tile[jr * 4 + 3][n]);
    *(ushort4*)(out + (size_t)(n0 + n) * K + k0 + jr * 4) = o;
  }
}

// ---------------------------------------------------------------------------
// GEMM1: 128m x 64n gate+up pair, K=768, BK=64.
// A: LDS via global_load_lds, double-buffered, XOR-swizzled.
// B: registers via direct global loads (K-contiguous weights, L2-resident),
//    double-buffered by parity in a fully-unrolled K-loop.
// Pipeline: issue 4 A-DMA + 8 B-loads for iter i+1, s_waitcnt vmcnt(12)
// drains exactly iter i's ops, raw s_barrier, compute.
// ---------------------------------------------------------------------------
__global__ __launch_bounds__(256, 2) void gemm_gu_mfma(
    const unsigned short* __restrict__ xb, const unsigned short* __restrict__ Wgt,
    const float* __restrict__ bgu, const int* __restrict__ e_cnt,
    const int* __restrict__ row_token, unsigned short* __restrict__ act) {
  int e = blockIdx.z;
  int cnt = e_cnt[e];
  int m0 = blockIdx.y * 128;
  if (m0 >= cnt) return;
  int n0 = blockIdx.x * 64;
  int start = e * CAP;
  const unsigned short* Wg = Wgt + (size_t)e * TWO_I * H;  // [f][h]
  const float* bias = bgu + (size_t)e * TWO_I;

  __shared__ short As[2][128 * 64];  // 32 KB
  __shared__ int tok[128];

  int tid = threadIdx.x;
  if (tid < 128) {
    int m = m0 + tid;
    tok[tid] = row_token[start + ((m < cnt) ? m : (cnt - 1))];
  }
  __syncthreads();

  int lane = tid & 63;
  int wave = tid >> 6;
  int quad = lane >> 4;
  int lrow = lane & 15;
  int wm = (wave >> 1) * 64;
  int wn = (wave & 1) * 32;

  // A staging addresses (k0 added per iter) + LDS offsets
  const unsigned short* gA[4];
  int oA[4];
#pragma unroll
  for (int r = 0; r < 4; r++) {
    int s = (wave * 4 + r) * 64 + lane;
    int row = s >> 3;
    int g = (s & 7) ^ (row & 7);
    gA[r] = xb + (size_t)tok[row] * H + g * 8;
    oA[r] = (wave * 4 + r) * 64 * 8;
  }

  // B fragment base pointers (per tj); fragment = 16B at base + k
  const unsigned short *bgp[2], *bup[2];
#pragma unroll
  for (int tj = 0; tj < 2; tj++) {
    int n = n0 + wn + tj * 16 + lrow;
    bgp[tj] = Wg + (size_t)n * H + quad * 8;
    bup[tj] = bgp[tj] + (size_t)I * H;
  }

  // bias preload (drained by the __syncthreads below)
  float bgv[2], buv[2];
#pragma unroll
  for (int tj = 0; tj < 2; tj++) {
    int ncol = n0 + wn + tj * 16 + lrow;
    bgv[tj] = bias[ncol];
    buv[tj] = bias[I + ncol];
  }

  floatx4 accg[4][2], accu[4][2];
#pragma unroll
  for (int i = 0; i < 4; i++)
#pragma unroll
    for (int j = 0; j < 2; j++) {
      accg[i][j] = floatx4{0.f, 0.f, 0.f, 0.f};
      accu[i][j] = floatx4{0.f, 0.f, 0.f, 0.f};
    }

  __syncthreads();  // full drain: in-loop vmcnt sees only pipeline ops

  // prologue: A buffer 0 (4 vm) + B parity 0 (8 vm)
#pragma unroll
  for (int r = 0; r < 4; r++) g2l16(gA[r], &As[0][oA[r]]);
  short8 bgq[2][2][2], buq[2][2][2];  // [parity][ks][tj]
#pragma unroll
  for (int ks = 0; ks < 2; ks++)
#pragma unroll
    for (int tj = 0; tj < 2; tj++) {
      bgq[0][ks][tj] = *(const short8*)(bgp[tj] + ks * 32);
      buq[0][ks][tj] = *(const short8*)(bup[tj] + ks * 32);
    }

  constexpr int NK = H / 64;  // 12
#pragma unroll
  for (int i = 0; i < NK; i++) {
    int cb = i & 1;
    int pc = i & 1, pn = pc ^ 1;
    if (i + 1 < NK) {
      int k1 = (i + 1) * 64;
#pragma unroll
      for (int r = 0; r < 4; r++) g2l16(gA[r] + k1, &As[cb ^ 1][oA[r]]);
#pragma unroll
      for (int ks = 0; ks < 2; ks++)
#pragma unroll
        for (int tj = 0; tj < 2; tj++) {
          bgq[pn][ks][tj] = *(const short8*)(bgp[tj] + k1 + ks * 32);
          buq[pn][ks][tj] = *(const short8*)(bup[tj] + k1 + ks * 32);
        }
      asm volatile("s_waitcnt vmcnt(12)" ::: "memory");
    } else {
      asm volatile("s_waitcnt vmcnt(0)" ::: "memory");
    }
    __builtin_amdgcn_s_barrier();

#pragma unroll
    for (int ks = 0; ks < 2; ks++) {
      int c = ks * 4 + quad;
      short8 a[4];
#pragma unroll
      for (int ti = 0; ti < 4; ti++) {
        int r = wm + ti * 16 + lrow;
        a[ti] = *(const short8*)(&As[cb][(r * 8 + (c ^ (r & 7))) * 8]);
      }
#pragma unroll
      for (int ti = 0; ti < 4; ti++)
#pragma unroll
        for (int tj = 0; tj < 2; tj++) {
          accg[ti][tj] = __builtin_amdgcn_mfma_f32_16x16x32_bf16(
              a[ti], bgq[pc][ks][tj], accg[ti][tj], 0, 0, 0);
          accu[ti][tj] = __builtin_amdgcn_mfma_f32_16x16x32_bf16(
              a[ti], buq[pc][ks][tj], accu[ti][tj], 0, 0, 0);
        }
    }
    __builtin_amdgcn_s_barrier();  // reads of As[cb] done before refill
  }

#pragma unroll
  for (int ti = 0; ti < 4; ti++) {
#pragma unroll
    for (int tj = 0; tj < 2; tj++) {
      int ncol = n0 + wn + tj * 16 + lrow;
#pragma unroll
      for (int r = 0; r < 4; r++) {
        int m = m0 + wm + ti * 16 + quad * 4 + r;
        if (m < cnt) {
          float g = accg[ti][tj][r] + bgv[tj];
          float u = accu[ti][tj][r] + buv[tj];
          g = fminf(g, LIMIT);
          u = fmaxf(fminf(u, LIMIT), -LIMIT);
          float glu = g / (1.0f + __expf(-ALPHA * g));
          act[(size_t)(start + m) * I + ncol] = f2bf((u + 1.0f) * glu);
        }
      }
    }
  }
}

// ---------------------------------------------------------------------------
// GEMM2: down = act @ Wd[e] (+bd), weighted atomic scatter. 128m x 64n,
// K=768, BK=64. A via LDS-DMA dbuf, B via registers (vmcnt(8)).
// ---------------------------------------------------------------------------
__global__ __launch_bounds__(256, 2) void gemm_down_mfma(
    const unsigned short* __restrict__ act, const unsigned short* __restrict__ Wdt,
    const float* __restrict__ bd, const int* __restrict__ e_cnt,
    const int* __restrict__ row_token, const float* __restrict__ row_w,
    float* __restrict__ out) {
  int e = blockIdx.z;
  int cnt = e_cnt[e];
  int m0 = blockIdx.y * 128;
  if (m0 >= cnt) return;
  int n0 = blockIdx.x * 64;
  int start = e * CAP;
  const unsigned short* Wd = Wdt + (size_t)e * H * I;  // [h][i]
  const float* bias = bd + (size_t)e * H;

  __shared__ short As[2][128 * 64];  // 32 KB
  __shared__ int tok[128];
  __shared__ float wts[128];

  int tid = threadIdx.x;
  if (tid < 128) {
    int m = m0 + tid;
    int mm = (m < cnt) ? m : (cnt - 1);
    tok[tid] = row_token[start + mm];
    wts[tid] = row_w[start + mm];
  }
  __syncthreads();

  int lane = tid & 63;
  int wave = tid >> 6;
  int quad = lane >> 4;
  int lrow = lane & 15;
  int wm = (wave >> 1) * 64;
  int wn = (wave & 1) * 32;

  const unsigned short* gA[4];
  int oA[4];
#pragma unroll
  for (int r = 0; r < 4; r++) {
    int s = (wave * 4 + r) * 64 + lane;
    int row = s >> 3;
    int g = (s & 7) ^ (row & 7);
    int gm = m0 + row;
    int mm = (gm < cnt) ? gm : (cnt - 1);
    gA[r] = act + (size_t)(start + mm) * I + g * 8;
    oA[r] = (wave * 4 + r) * 64 * 8;
  }

  const unsigned short* bp[2];
#pragma unroll
  for (int tj = 0; tj < 2; tj++) {
    int n = n0 + wn + tj * 16 + lrow;
    bp[tj] = Wd + (size_t)n * I + quad * 8;
  }

  float bdv[2];
#pragma unroll
  for (int tj = 0; tj < 2; tj++) bdv[tj] = bias[n0 + wn + tj * 16 + lrow];

  floatx4 acc[4][2];
#pragma unroll
  for (int i = 0; i < 4; i++)
#pragma unroll
    for (int j = 0; j < 2; j++) acc[i][j] = floatx4{0.f, 0.f, 0.f, 0.f};

  __syncthreads();  // full drain

#pragma unroll
  for (int r = 0; r < 4; r++) g2l16(gA[r], &As[0][oA[r]]);
  short8 bq[2][2][2];  // [parity][ks][tj]
#pragma unroll
  for (int ks = 0; ks < 2; ks++)
#pragma unroll
    for (int tj = 0; tj < 2; tj++)
      bq[0][ks][tj] = *(const short8*)(bp[tj] + ks * 32);

  constexpr int NK = I / 64;  // 12
#pragma unroll
  for (int i = 0; i < NK; i++) {
    int cb = i & 1;
    int pc = i & 1, pn = pc ^ 1;
    if (i + 1 < NK) {
      int k1 = (i + 1) * 64;
#pragma unroll
      for (int r = 0; r < 4; r++) g2l16(gA[r] + k1, &As[cb ^ 1][oA[r]]);
#pragma unroll
      for (int ks = 0; ks < 2; ks++)
#pragma unroll
        for (int tj = 0; tj < 2; tj++)
          bq[pn][ks][tj] = *(const short8*)(bp[tj] + k1 + ks * 32);
      asm volatile("s_waitcnt vmcnt(8)" ::: "memory");
    } else {
      asm volatile("s_waitcnt vmcnt(0)" ::: "memory");
    }
    __builtin_amdgcn_s_barrier();

#pragma unroll
    for (int ks = 0; ks < 2; ks++) {
      int c = ks * 4 + quad;
      short8 a[4];
#pragma unroll
      for (int ti = 0; ti < 4; ti++) {
        int r = wm + ti * 16 + lrow;
        a[ti] = *(const short8*)(&As[cb][(r * 8 + (c ^ (r & 7))) * 8]);
      }
#pragma unroll
      for (int ti = 0; ti < 4; ti++)
#pragma unroll
        for (int tj = 0; tj < 2; tj++)
          acc[ti][tj] = __builtin_amdgcn_mfma_f32_16x16x32_bf16(
              a[ti], bq[pc][ks][tj], acc[ti][tj], 0, 0, 0);
    }
    __builtin_amdgcn_s_barrier();
  }

#pragma unroll
  for (int ti = 0; ti < 4; ti++) {
#pragma unroll
    for (int tj = 0; tj < 2; tj++) {
      int ncol = n0 + wn + tj * 16 + lrow;
#pragma unroll
      for (int r = 0; r < 4; r++) {
        int ml = wm + ti * 16 + quad * 4 + r;
        int m = m0 + ml;
        if (m < cnt) {
          atomicAdd(&out[(size_t)tok[ml] * H + ncol],
                    wts[ml] * (acc[ti][tj][r] + bdv[tj]));
        }
      }
    }
  }
}

// ---------------------------------------------------------------------------
extern "C" void kernel_launch(void* const* d_in, const int* in_sizes, int n_in,
                              void* d_out, int out_size, void* d_ws,
                              size_t ws_size, hipStream_t stream) {
  const float* x   = (const float*)d_in[0];
  const float* Wr  = (const float*)d_in[1];
  const float* br  = (const float*)d_in[2];
  const float* Wgu = (const float*)d_in[3];
  const float* bgu = (const float*)d_in[4];
  const float* Wd  = (const float*)d_in[5];
  const float* bd  = (const float*)d_in[6];
  float* out = (float*)d_out;

  char* w = (char*)d_ws;
  int* e_cnt = (int*)w;       w += 16 * sizeof(int);
  int* topk_idx = (int*)w;    w += (size_t)T * 2 * sizeof(int);
  float* topk_w = (float*)w;  w += (size_t)T * 2 * sizeof(float);
  int* row_token = (int*)w;   w += (size_t)E * CAP * sizeof(int);
  float* row_w = (float*)w;   w += (size_t)E * CAP * sizeof(float);
  unsigned short* xb  = (unsigned short*)w; w += (size_t)T * H * 2;         // 3.1 MB
  unsigned short* Wgt = (unsigned short*)w; w += (size_t)E * TWO_I * H * 2; // 18.9 MB
  unsigned short* Wdt = (unsigned short*)w; w += (size_t)E * H * I * 2;     // 9.4 MB
  unsigned short* act = (unsigned short*)w; w += (size_t)E * CAP * I * 2;   // 25.2 MB

  router_kernel<<<T, 64, 0, stream>>>(x, Wr, br, topk_idx, topk_w, xb, out);
  transpose_all<<<dim3(TWO_I / 64, H / 64, 17), 256, 0, stream>>>(
      Wgu, Wd, Wgt, Wdt, topk_idx, topk_w, e_cnt, row_token, row_w);
  gemm_gu_mfma<<<dim3(I / 64, CAP / 128, E), 256, 0, stream>>>(
      xb, Wgt, bgu, e_cnt, row_token, act);
  gemm_down_mfma<<<dim3(H / 64, CAP / 128, E), 256, 0, stream>>>(
      act, Wdt, bd, e_cnt, row_token, row_w, out);
}

// Round 8
// 166.978 us; speedup vs baseline: 1.2796x; 1.2796x over previous
//
#include <hip/hip_runtime.h>
#include <hip/hip_bf16.h>
#include <cmath>

#define ALPHA 1.702f
#define LIMIT 7.0f

constexpr int B = 2, S = 1024, H = 768, E = 8, I = 768;
constexpr int T = B * S;          // 2048 tokens
constexpr int TWO_I = 2 * I;      // 1536
constexpr int CAP = T;            // per-expert row capacity
constexpr int NROWS = T * 2;      // 4096 (token, expert) entries
constexpr int NT1 = I / 64;       // 12 n-tiles (gemm1)
constexpr int NT2 = H / 64;       // 12 n-tiles (gemm2)
constexpr int MT = CAP / 128;     // 16 m-tiles

typedef __attribute__((ext_vector_type(8))) short short8;
typedef __attribute__((ext_vector_type(4))) float floatx4;

__device__ __forceinline__ unsigned short f2bf(float v) {
  __hip_bfloat16 h = __float2bfloat16(v);
  return *reinterpret_cast<unsigned short*>(&h);
}

// async global->LDS, 16B per lane. LDS dst is wave-uniform base + lane*16.
__device__ __forceinline__ void g2l16(const void* g, void* l) {
  __builtin_amdgcn_global_load_lds(
      (const __attribute__((address_space(1))) void*)g,
      (__attribute__((address_space(3))) void*)l, 16, 0, 0);
}

// ---------------------------------------------------------------------------
// Router: 1 wave/token. Fused: logits+top2+softmax, bf16 cast of x,
// zero-init of out row. No global atomics.
// ---------------------------------------------------------------------------
__global__ __launch_bounds__(64) void router_kernel(
    const float* __restrict__ x, const float* __restrict__ Wr,
    const float* __restrict__ br, int* __restrict__ topk_idx,
    float* __restrict__ topk_w, unsigned short* __restrict__ xb,
    float* __restrict__ out) {
  int t = blockIdx.x;
  int lane = threadIdx.x;  // 0..63
  const float* xr = x + (size_t)t * H;

  float4 z4 = {0.f, 0.f, 0.f, 0.f};
#pragma unroll
  for (int j = 0; j < 3; j++)
    *(float4*)(out + (size_t)t * H + (size_t)(j * 64 + lane) * 4) = z4;

  float acc[E];
#pragma unroll
  for (int e = 0; e < E; e++) acc[e] = 0.0f;

#pragma unroll
  for (int it = 0; it < 3; it++) {
    int h4 = it * 64 + lane;  // float4 index into the row
    float4 xv = *(const float4*)(xr + (size_t)h4 * 4);
    ushort4 xo;
    xo.x = f2bf(xv.x);
    xo.y = f2bf(xv.y);
    xo.z = f2bf(xv.z);
    xo.w = f2bf(xv.w);
    *(ushort4*)(xb + (size_t)t * H + (size_t)h4 * 4) = xo;
    const float* wrow = Wr + (size_t)h4 * 4 * E;
    float xs[4] = {xv.x, xv.y, xv.z, xv.w};
#pragma unroll
    for (int j = 0; j < 4; j++)
#pragma unroll
      for (int e = 0; e < E; e++) acc[e] += xs[j] * wrow[j * E + e];
  }
#pragma unroll
  for (int e = 0; e < E; e++) {
    float v = acc[e];
    for (int off = 32; off > 0; off >>= 1) v += __shfl_down(v, off, 64);
    acc[e] = v;
  }
  if (lane == 0) {
    float logits[E];
#pragma unroll
    for (int e = 0; e < E; e++) logits[e] = acc[e] + br[e];
    int i0 = 0;
    float v0 = logits[0];
#pragma unroll
    for (int e = 1; e < E; e++)
      if (logits[e] > v0) { v0 = logits[e]; i0 = e; }
    int i1 = -1;
    float v1 = -INFINITY;
#pragma unroll
    for (int e = 0; e < E; e++) {
      if (e == i0) continue;
      if (logits[e] > v1) { v1 = logits[e]; i1 = e; }
    }
    float s1 = __expf(v1 - v0);
    float denom = 1.0f + s1;
    topk_idx[t * 2 + 0] = i0;
    topk_idx[t * 2 + 1] = i1;
    topk_w[t * 2 + 0] = 1.0f / denom;
    topk_w[t * 2 + 1] = s1 / denom;
  }
}

// ---------------------------------------------------------------------------
// Transpose + cast both weight tensors; z==16 slice = single-block
// assignment pass (LDS atomics), hidden under this dispatch.
// ---------------------------------------------------------------------------
__global__ __launch_bounds__(256) void transpose_all(
    const float* __restrict__ Wgu, const float* __restrict__ Wd,
    unsigned short* __restrict__ Wgt, unsigned short* __restrict__ Wdt,
    const int* __restrict__ topk_idx, const float* __restrict__ topk_w,
    int* __restrict__ e_cnt, int* __restrict__ row_token,
    float* __restrict__ row_w) {
  int z = blockIdx.z;
  int tid = threadIdx.x;

  if (z == 16) {
    if (blockIdx.x != 0 || blockIdx.y != 0) return;
    __shared__ int cur[E];
    if (tid < E) cur[tid] = 0;
    __syncthreads();
    for (int i = tid; i < NROWS; i += 256) {
      int e = topk_idx[i];
      int pos = atomicAdd(&cur[e], 1);
      row_token[e * CAP + pos] = i >> 1;
      row_w[e * CAP + pos] = topk_w[i];
    }
    __syncthreads();
    if (tid < E) e_cnt[tid] = cur[tid];
    return;
  }

  int which = z >> 3, e = z & 7;
  int N = which ? H : TWO_I;
  if (which && blockIdx.x >= (H / 64)) return;
  const float* in = which ? (Wd + (size_t)e * H * I)
                          : (Wgu + (size_t)e * H * TWO_I);
  unsigned short* out = which ? (Wdt + (size_t)e * H * I)
                              : (Wgt + (size_t)e * H * TWO_I);
  constexpr int K = 768;
  int n0 = blockIdx.x * 64, k0 = blockIdx.y * 64;

  __shared__ float tile[64][65];
  int jr = tid & 15, r0 = tid >> 4;
#pragma unroll
  for (int p = 0; p < 4; p++) {
    int k = r0 + p * 16;
    float4 v = *(const float4*)(in + (size_t)(k0 + k) * N + n0 + jr * 4);
    tile[k][jr * 4 + 0] = v.x;
    tile[k][jr * 4 + 1] = v.y;
    tile[k][jr * 4 + 2] = v.z;
    tile[k][jr * 4 + 3] = v.w;
  }
  __syncthreads();
#pragma unroll
  for (int p = 0; p < 4; p++) {
    int n = r0 + p * 16;
    ushort4 o;
    o.x = f2bf(tile[jr * 4 + 0][n]);
    o.y = f2bf(tile[jr * 4 + 1][n]);
    o.z = f2bf(tile[jr * 4 + 2][n]);
    o.w = f2bf(tile[jr * 4 + 3][n]);
    *(ushort4*)(out + (size_t)(n0 + n) * K + k0 + jr * 4) = o;
  }
}

// ---------------------------------------------------------------------------
// GEMM1: 128m x 64n gate+up pair, K=768, BK=64, XOR-swizzled LDS,
// double-buffered async pipeline (raw s_barrier + s_waitcnt vmcnt(8)).
// 1D grid, XCD-swizzled: bid = m*96 + (e*12 + n) so all 16 m-tiles sharing
// a B-slab (e,n) hit the SAME XCD (stride 96 = 0 mod 8) -> B stays L2-hot
// (12 slabs * 236 KB = 2.8 MB < 4 MB L2). R6 lesson: B slab re-fetch from
// HBM across XCDs cost 2x FETCH of Wgt.
// ---------------------------------------------------------------------------
__global__ __launch_bounds__(256) void gemm_gu_mfma(
    const unsigned short* __restrict__ xb, const unsigned short* __restrict__ Wgt,
    const float* __restrict__ bgu, const int* __restrict__ e_cnt,
    const int* __restrict__ row_token, unsigned short* __restrict__ act) {
  int bid = blockIdx.x;
  int g = bid % (E * NT1);       // (e*12 + n), fixed XCD = g%8
  int mt = bid / (E * NT1);      // m-tile
  int e = g / NT1;
  int n0 = (g % NT1) * 64;
  int cnt = e_cnt[e];
  int m0 = mt * 128;
  if (m0 >= cnt) return;
  int start = e * CAP;
  const unsigned short* Wg = Wgt + (size_t)e * TWO_I * H;  // [f][h]
  const float* bias = bgu + (size_t)e * TWO_I;

  __shared__ short As[2][128 * 64];  // 32 KB
  __shared__ short Bg[2][64 * 64];   // 16 KB
  __shared__ short Bu[2][64 * 64];   // 16 KB
  __shared__ int tok[128];

  int tid = threadIdx.x;
  if (tid < 128) {
    int m = m0 + tid;
    tok[tid] = row_token[start + ((m < cnt) ? m : (cnt - 1))];
  }
  __syncthreads();

  int lane = tid & 63;
  int wave = tid >> 6;
  int quad = lane >> 4;
  int lrow = lane & 15;
  int wm = (wave >> 1) * 64;
  int wn = (wave & 1) * 32;

  const unsigned short* gA[4];
  int oA[4];
#pragma unroll
  for (int r = 0; r < 4; r++) {
    int s = (wave * 4 + r) * 64 + lane;
    int row = s >> 3;
    int gg = (s & 7) ^ (row & 7);
    gA[r] = xb + (size_t)tok[row] * H + gg * 8;
    oA[r] = (wave * 4 + r) * 64 * 8;
  }
  const unsigned short *gBg[2], *gBu[2];
  int oB[2];
#pragma unroll
  for (int r = 0; r < 2; r++) {
    int s = (wave * 2 + r) * 64 + lane;
    int row = s >> 3;
    int gg = (s & 7) ^ (row & 7);
    gBg[r] = Wg + (size_t)(n0 + row) * H + gg * 8;
    gBu[r] = gBg[r] + (size_t)I * H;
    oB[r] = (wave * 2 + r) * 64 * 8;
  }

  float bgv[2], buv[2];
#pragma unroll
  for (int tj = 0; tj < 2; tj++) {
    int ncol = n0 + wn + tj * 16 + lrow;
    bgv[tj] = bias[ncol];
    buv[tj] = bias[I + ncol];
  }

  floatx4 accg[4][2], accu[4][2];
#pragma unroll
  for (int i = 0; i < 4; i++)
#pragma unroll
    for (int j = 0; j < 2; j++) {
      accg[i][j] = floatx4{0.f, 0.f, 0.f, 0.f};
      accu[i][j] = floatx4{0.f, 0.f, 0.f, 0.f};
    }

  __syncthreads();  // drain so in-loop vmcnt sees only staging DMAs

#pragma unroll
  for (int r = 0; r < 4; r++) g2l16(gA[r], &As[0][oA[r]]);
#pragma unroll
  for (int r = 0; r < 2; r++) {
    g2l16(gBg[r], &Bg[0][oB[r]]);
    g2l16(gBu[r], &Bu[0][oB[r]]);
  }

  constexpr int NK = H / 64;  // 12
  for (int i = 0; i < NK; i++) {
    int cb = i & 1;
    if (i + 1 < NK) {
      int nb = cb ^ 1;
      int k1 = (i + 1) * 64;
#pragma unroll
      for (int r = 0; r < 4; r++) g2l16(gA[r] + k1, &As[nb][oA[r]]);
#pragma unroll
      for (int r = 0; r < 2; r++) {
        g2l16(gBg[r] + k1, &Bg[nb][oB[r]]);
        g2l16(gBu[r] + k1, &Bu[nb][oB[r]]);
      }
      asm volatile("s_waitcnt vmcnt(8)" ::: "memory");
    } else {
      asm volatile("s_waitcnt vmcnt(0)" ::: "memory");
    }
    __builtin_amdgcn_s_barrier();

#pragma unroll
    for (int ks = 0; ks < 2; ks++) {
      int c = ks * 4 + quad;
      short8 a[4], bg[2], bu[2];
#pragma unroll
      for (int ti = 0; ti < 4; ti++) {
        int r = wm + ti * 16 + lrow;
        a[ti] = *(const short8*)(&As[cb][(r * 8 + (c ^ (r & 7))) * 8]);
      }
#pragma unroll
      for (int tj = 0; tj < 2; tj++) {
        int r = wn + tj * 16 + lrow;
        bg[tj] = *(const short8*)(&Bg[cb][(r * 8 + (c ^ (r & 7))) * 8]);
        bu[tj] = *(const short8*)(&Bu[cb][(r * 8 + (c ^ (r & 7))) * 8]);
      }
#pragma unroll
      for (int ti = 0; ti < 4; ti++)
#pragma unroll
        for (int tj = 0; tj < 2; tj++) {
          accg[ti][tj] = __builtin_amdgcn_mfma_f32_16x16x32_bf16(
              a[ti], bg[tj], accg[ti][tj], 0, 0, 0);
          accu[ti][tj] = __builtin_amdgcn_mfma_f32_16x16x32_bf16(
              a[ti], bu[tj], accu[ti][tj], 0, 0, 0);
        }
    }
    __builtin_amdgcn_s_barrier();  // reads of cb done before refill
  }

#pragma unroll
  for (int ti = 0; ti < 4; ti++) {
#pragma unroll
    for (int tj = 0; tj < 2; tj++) {
      int ncol = n0 + wn + tj * 16 + lrow;
#pragma unroll
      for (int r = 0; r < 4; r++) {
        int m = m0 + wm + ti * 16 + quad * 4 + r;
        if (m < cnt) {
          float gg = accg[ti][tj][r] + bgv[tj];
          float u = accu[ti][tj][r] + buv[tj];
          gg = fminf(gg, LIMIT);
          u = fmaxf(fminf(u, LIMIT), -LIMIT);
          float glu = gg / (1.0f + __expf(-ALPHA * gg));
          act[(size_t)(start + m) * I + ncol] = f2bf((u + 1.0f) * glu);
        }
      }
    }
  }
}

// ---------------------------------------------------------------------------
// GEMM2: down = act @ Wd[e] (+bd), weighted atomic scatter. 128m x 64n,
// K=768, BK=64, XOR swizzle, double-buffered (vmcnt(6)).
// Same 1D XCD-swizzled grid as gemm1 (Wd slabs: 12 * 118 KB = 1.4 MB / XCD).
// ---------------------------------------------------------------------------
__global__ __launch_bounds__(256) void gemm_down_mfma(
    const unsigned short* __restrict__ act, const unsigned short* __restrict__ Wdt,
    const float* __restrict__ bd, const int* __restrict__ e_cnt,
    const int* __restrict__ row_token, const float* __restrict__ row_w,
    float* __restrict__ out) {
  int bid = blockIdx.x;
  int g = bid % (E * NT2);
  int mt = bid / (E * NT2);
  int e = g / NT2;
  int n0 = (g % NT2) * 64;
  int cnt = e_cnt[e];
  int m0 = mt * 128;
  if (m0 >= cnt) return;
  int start = e * CAP;
  const unsigned short* Wd = Wdt + (size_t)e * H * I;  // [h][i]
  const float* bias = bd + (size_t)e * H;

  __shared__ short As[2][128 * 64];  // 32 KB
  __shared__ short Bs[2][64 * 64];   // 16 KB
  __shared__ int tok[128];
  __shared__ float wts[128];

  int tid = threadIdx.x;
  if (tid < 128) {
    int m = m0 + tid;
    int mm = (m < cnt) ? m : (cnt - 1);
    tok[tid] = row_token[start + mm];
    wts[tid] = row_w[start + mm];
  }
  __syncthreads();

  int lane = tid & 63;
  int wave = tid >> 6;
  int quad = lane >> 4;
  int lrow = lane & 15;
  int wm = (wave >> 1) * 64;
  int wn = (wave & 1) * 32;

  const unsigned short* gA[4];
  int oA[4];
#pragma unroll
  for (int r = 0; r < 4; r++) {
    int s = (wave * 4 + r) * 64 + lane;
    int row = s >> 3;
    int gg = (s & 7) ^ (row & 7);
    int gm = m0 + row;
    int mm = (gm < cnt) ? gm : (cnt - 1);
    gA[r] = act + (size_t)(start + mm) * I + gg * 8;
    oA[r] = (wave * 4 + r) * 64 * 8;
  }
  const unsigned short* gB[2];
  int oB[2];
#pragma unroll
  for (int r = 0; r < 2; r++) {
    int s = (wave * 2 + r) * 64 + lane;
    int row = s >> 3;
    int gg = (s & 7) ^ (row & 7);
    gB[r] = Wd + (size_t)(n0 + row) * I + gg * 8;
    oB[r] = (wave * 2 + r) * 64 * 8;
  }

  float bdv[2];
#pragma unroll
  for (int tj = 0; tj < 2; tj++) bdv[tj] = bias[n0 + wn + tj * 16 + lrow];

  floatx4 acc[4][2];
#pragma unroll
  for (int i = 0; i < 4; i++)
#pragma unroll
    for (int j = 0; j < 2; j++) acc[i][j] = floatx4{0.f, 0.f, 0.f, 0.f};

  __syncthreads();  // drain; in-loop vmcnt sees only the 6 staging DMAs

#pragma unroll
  for (int r = 0; r < 4; r++) g2l16(gA[r], &As[0][oA[r]]);
#pragma unroll
  for (int r = 0; r < 2; r++) g2l16(gB[r], &Bs[0][oB[r]]);

  constexpr int NK = I / 64;  // 12
  for (int i = 0; i < NK; i++) {
    int cb = i & 1;
    if (i + 1 < NK) {
      int nb = cb ^ 1;
      int k1 = (i + 1) * 64;
#pragma unroll
      for (int r = 0; r < 4; r++) g2l16(gA[r] + k1, &As[nb][oA[r]]);
#pragma unroll
      for (int r = 0; r < 2; r++) g2l16(gB[r] + k1, &Bs[nb][oB[r]]);
      asm volatile("s_waitcnt vmcnt(6)" ::: "memory");
    } else {
      asm volatile("s_waitcnt vmcnt(0)" ::: "memory");
    }
    __builtin_amdgcn_s_barrier();

#pragma unroll
    for (int ks = 0; ks < 2; ks++) {
      int c = ks * 4 + quad;
      short8 a[4], b[2];
#pragma unroll
      for (int ti = 0; ti < 4; ti++) {
        int r = wm + ti * 16 + lrow;
        a[ti] = *(const short8*)(&As[cb][(r * 8 + (c ^ (r & 7))) * 8]);
      }
#pragma unroll
      for (int tj = 0; tj < 2; tj++) {
        int r = wn + tj * 16 + lrow;
        b[tj] = *(const short8*)(&Bs[cb][(r * 8 + (c ^ (r & 7))) * 8]);
      }
#pragma unroll
      for (int ti = 0; ti < 4; ti++)
#pragma unroll
        for (int tj = 0; tj < 2; tj++)
          acc[ti][tj] = __builtin_amdgcn_mfma_f32_16x16x32_bf16(
              a[ti], b[tj], acc[ti][tj], 0, 0, 0);
    }
    __builtin_amdgcn_s_barrier();
  }

#pragma unroll
  for (int ti = 0; ti < 4; ti++) {
#pragma unroll
    for (int tj = 0; tj < 2; tj++) {
      int ncol = n0 + wn + tj * 16 + lrow;
#pragma unroll
      for (int r = 0; r < 4; r++) {
        int ml = wm + ti * 16 + quad * 4 + r;
        int m = m0 + ml;
        if (m < cnt) {
          atomicAdd(&out[(size_t)tok[ml] * H + ncol],
                    wts[ml] * (acc[ti][tj][r] + bdv[tj]));
        }
      }
    }
  }
}

// ---------------------------------------------------------------------------
extern "C" void kernel_launch(void* const* d_in, const int* in_sizes, int n_in,
                              void* d_out, int out_size, void* d_ws,
                              size_t ws_size, hipStream_t stream) {
  const float* x   = (const float*)d_in[0];
  const float* Wr  = (const float*)d_in[1];
  const float* br  = (const float*)d_in[2];
  const float* Wgu = (const float*)d_in[3];
  const float* bgu = (const float*)d_in[4];
  const float* Wd  = (const float*)d_in[5];
  const float* bd  = (const float*)d_in[6];
  float* out = (float*)d_out;

  char* w = (char*)d_ws;
  int* e_cnt = (int*)w;       w += 16 * sizeof(int);
  int* topk_idx = (int*)w;    w += (size_t)T * 2 * sizeof(int);
  float* topk_w = (float*)w;  w += (size_t)T * 2 * sizeof(float);
  int* row_token = (int*)w;   w += (size_t)E * CAP * sizeof(int);
  float* row_w = (float*)w;   w += (size_t)E * CAP * sizeof(float);
  unsigned short* xb  = (unsigned short*)w; w += (size_t)T * H * 2;         // 3.1 MB
  unsigned short* Wgt = (unsigned short*)w; w += (size_t)E * TWO_I * H * 2; // 18.9 MB
  unsigned short* Wdt = (unsigned short*)w; w += (size_t)E * H * I * 2;     // 9.4 MB
  unsigned short* act = (unsigned short*)w; w += (size_t)E * CAP * I * 2;   // 25.2 MB

  router_kernel<<<T, 64, 0, stream>>>(x, Wr, br, topk_idx, topk_w, xb, out);
  transpose_all<<<dim3(TWO_I / 64, H / 64, 17), 256, 0, stream>>>(
      Wgu, Wd, Wgt, Wdt, topk_idx, topk_w, e_cnt, row_token, row_w);
  gemm_gu_mfma<<<dim3(MT * E * NT1), 256, 0, stream>>>(
      xb, Wgt, bgu, e_cnt, row_token, act);
  gemm_down_mfma<<<dim3(MT * E * NT2), 256, 0, stream>>>(
      act, Wdt, bd, e_cnt, row_token, row_w, out);
}